// Round 1
// baseline (867.425 us; speedup 1.0000x reference)
//
#include <hip/hip_runtime.h>
#include <hip/hip_bf16.h>
#include <stdint.h>

#define NNODES 50000
#define NEDGES 800000
#define NF 128
#define NH 256

typedef __attribute__((ext_vector_type(8))) __bf16 bf16x8;
typedef __attribute__((ext_vector_type(4))) float f32x4;

__device__ __forceinline__ unsigned short f2bf(float f) {
    union { float f; unsigned int u; } v; v.f = f;
    unsigned int r = v.u + 0x7fffu + ((v.u >> 16) & 1u);
    return (unsigned short)(r >> 16);
}

__device__ __forceinline__ void gload16(const void* g, void* l) {
    __builtin_amdgcn_global_load_lds(
        (const __attribute__((address_space(1))) void*)g,
        (__attribute__((address_space(3))) void*)l,
        16, 0, 0);
}

// f32 -> bf16 (vectorized), n4 = count of float4 groups
__global__ __launch_bounds__(256) void cvt_kernel(const float* __restrict__ src,
                                                  unsigned short* __restrict__ dst, int n4) {
    int i = blockIdx.x * 256 + threadIdx.x;
    if (i < n4) {
        const float4 v = ((const float4*)src)[i];
        ushort4 o;
        o.x = f2bf(v.x); o.y = f2bf(v.y); o.z = f2bf(v.z); o.w = f2bf(v.w);
        ((ushort4*)dst)[i] = o;
    }
}

// W [K][Nn] f32 row-major -> Wt [Nn][K] bf16
__global__ __launch_bounds__(256) void tcvt_kernel(const float* __restrict__ W,
                                                   unsigned short* __restrict__ Wt, int K, int Nn) {
    int i = blockIdx.x * 256 + threadIdx.x;
    if (i < K * Nn) {
        int k = i / Nn, n = i - k * Nn;
        Wt[n * K + k] = f2bf(W[i]);
    }
}

// ---------------- edge kernel ----------------
// 64 edges per block, 4 waves, wave w owns output cols [w*64, w*64+64)
__global__ __launch_bounds__(256, 2)
void edge_kernel(const unsigned short* __restrict__ hbf,
                 const int* __restrict__ ei,
                 const unsigned short* __restrict__ Wt1,
                 const unsigned short* __restrict__ Wt2,
                 const float* __restrict__ b1, const float* __restrict__ g1,
                 const float* __restrict__ be1, const float* __restrict__ b2,
                 float* __restrict__ agg)
{
    __shared__ __align__(16) unsigned short A_lds[64 * 64];
    __shared__ __align__(16) unsigned short B_lds[256 * 64];
    __shared__ __align__(16) unsigned short M_lds[64 * 256];
    __shared__ int s_src[64], s_dst[64];
    __shared__ float s_mr[64][2];
    __shared__ float s_b1[256], s_g1[256], s_be1[256], s_b2[256];

    const int tid = threadIdx.x;
    const int lane = tid & 63;
    const int w = tid >> 6;
    const int l15 = lane & 15;
    const int g = lane >> 4;
    const int e0 = blockIdx.x * 64;

    if (tid < 64) s_src[tid] = ei[e0 + tid];
    else if (tid < 128) s_dst[tid - 64] = ei[NEDGES + e0 + (tid - 64)];
    s_b1[tid] = b1[tid]; s_g1[tid] = g1[tid]; s_be1[tid] = be1[tid]; s_b2[tid] = b2[tid];
    __syncthreads();

    f32x4 acc[4][4] = {};

    // ---- GEMM1: e_in[64x256] @ W1 ----
    for (int kt = 0; kt < 4; ++kt) {
        #pragma unroll
        for (int i = 0; i < 2; ++i) {
            int c = i * 256 + w * 64 + lane;
            int r = c >> 3, kbl = c & 7;
            int kb = kbl ^ (r & 7);
            int nd = (kt < 2) ? s_src[r] : s_dst[r];
            const unsigned short* src = hbf + nd * NF + (kt & 1) * 64 + kb * 8;
            gload16(src, &A_lds[(i * 256 + w * 64) * 8]);
        }
        #pragma unroll
        for (int i = 0; i < 8; ++i) {
            int c = i * 256 + w * 64 + lane;
            int n = c >> 3, kbl = c & 7;
            int kb = kbl ^ (n & 7);
            const unsigned short* src = Wt1 + n * 256 + kt * 64 + kb * 8;
            gload16(src, &B_lds[(i * 256 + w * 64) * 8]);
        }
        __syncthreads();
        #pragma unroll
        for (int kk = 0; kk < 2; ++kk) {
            int ke = kk * 32 + 8 * g;
            bf16x8 af[4], bfr[4];
            #pragma unroll
            for (int m = 0; m < 4; ++m) {
                int r = m * 16 + l15;
                af[m] = *(const bf16x8*)(const void*)&A_lds[r * 64 + (ke ^ ((r & 7) << 3))];
            }
            #pragma unroll
            for (int n = 0; n < 4; ++n) {
                int cn = w * 64 + n * 16 + l15;
                bfr[n] = *(const bf16x8*)(const void*)&B_lds[cn * 64 + (ke ^ ((cn & 7) << 3))];
            }
            #pragma unroll
            for (int m = 0; m < 4; ++m)
                #pragma unroll
                for (int n = 0; n < 4; ++n)
                    acc[m][n] = __builtin_amdgcn_mfma_f32_16x16x32_bf16(af[m], bfr[n], acc[m][n], 0, 0, 0);
        }
        __syncthreads();
    }

    // ---- bias + LayerNorm stats ----
    float psum[4][4], psq[4][4];
    #pragma unroll
    for (int m = 0; m < 4; ++m)
        #pragma unroll
        for (int rr = 0; rr < 4; ++rr) { psum[m][rr] = 0.f; psq[m][rr] = 0.f; }
    #pragma unroll
    for (int m = 0; m < 4; ++m)
        #pragma unroll
        for (int n = 0; n < 4; ++n) {
            int col = w * 64 + n * 16 + l15;
            float bb = s_b1[col];
            #pragma unroll
            for (int rr = 0; rr < 4; ++rr) {
                float x = acc[m][n][rr] + bb;
                acc[m][n][rr] = x;
                psum[m][rr] += x;
                psq[m][rr] += x * x;
            }
        }
    #pragma unroll
    for (int m = 0; m < 4; ++m)
        #pragma unroll
        for (int rr = 0; rr < 4; ++rr) {
            float s = psum[m][rr], q = psq[m][rr];
            s += __shfl_xor(s, 1); s += __shfl_xor(s, 2); s += __shfl_xor(s, 4); s += __shfl_xor(s, 8);
            q += __shfl_xor(q, 1); q += __shfl_xor(q, 2); q += __shfl_xor(q, 4); q += __shfl_xor(q, 8);
            psum[m][rr] = s; psq[m][rr] = q;
        }
    float vs = 0.f, vq = 0.f;
    #pragma unroll
    for (int m = 0; m < 4; ++m)
        #pragma unroll
        for (int rr = 0; rr < 4; ++rr) {
            bool sel = (l15 == m * 4 + rr);
            vs = sel ? psum[m][rr] : vs;
            vq = sel ? psq[m][rr] : vq;
        }
    float (*s_part)[64][2] = (float(*)[64][2])(void*)M_lds;  // overlay, dead before M writes
    {
        int row = (l15 >> 2) * 16 + 4 * g + (l15 & 3);
        s_part[w][row][0] = vs;
        s_part[w][row][1] = vq;
    }
    __syncthreads();
    if (tid < 64) {
        float s = s_part[0][tid][0] + s_part[1][tid][0] + s_part[2][tid][0] + s_part[3][tid][0];
        float q = s_part[0][tid][1] + s_part[1][tid][1] + s_part[2][tid][1] + s_part[3][tid][1];
        float mean = s * (1.f / 256.f);
        float var = q * (1.f / 256.f) - mean * mean;
        s_mr[tid][0] = mean;
        s_mr[tid][1] = rsqrtf(var + 1e-5f);
    }
    __syncthreads();

    // ---- LN apply + SiLU + write m tile (bf16, swizzled) ----
    #pragma unroll
    for (int m = 0; m < 4; ++m)
        #pragma unroll
        for (int rr = 0; rr < 4; ++rr) {
            int row = m * 16 + 4 * g + rr;
            float mean = s_mr[row][0], rstd = s_mr[row][1];
            #pragma unroll
            for (int n = 0; n < 4; ++n) {
                int col = w * 64 + n * 16 + l15;
                float y = (acc[m][n][rr] - mean) * rstd * s_g1[col] + s_be1[col];
                float sy = y * (1.f / (1.f + __expf(-y)));
                M_lds[row * 256 + (col ^ ((row & 7) << 3))] = f2bf(sy);
            }
        }
    __syncthreads();

    // ---- GEMM2: m[64x256] @ W2 ----
    f32x4 acc2[4][4] = {};
    for (int kt = 0; kt < 4; ++kt) {
        #pragma unroll
        for (int i = 0; i < 8; ++i) {
            int c = i * 256 + w * 64 + lane;
            int n = c >> 3, kbl = c & 7;
            int kb = kbl ^ (n & 7);
            const unsigned short* src = Wt2 + n * 256 + kt * 64 + kb * 8;
            gload16(src, &B_lds[(i * 256 + w * 64) * 8]);
        }
        __syncthreads();
        #pragma unroll
        for (int kk = 0; kk < 2; ++kk) {
            int keB = kk * 32 + 8 * g;
            int keA = kt * 64 + keB;
            bf16x8 af[4], bfr[4];
            #pragma unroll
            for (int m = 0; m < 4; ++m) {
                int r = m * 16 + l15;
                af[m] = *(const bf16x8*)(const void*)&M_lds[r * 256 + (keA ^ ((r & 7) << 3))];
            }
            #pragma unroll
            for (int n = 0; n < 4; ++n) {
                int cn = w * 64 + n * 16 + l15;
                bfr[n] = *(const bf16x8*)(const void*)&B_lds[cn * 64 + (keB ^ ((cn & 7) << 3))];
            }
            #pragma unroll
            for (int m = 0; m < 4; ++m)
                #pragma unroll
                for (int n = 0; n < 4; ++n)
                    acc2[m][n] = __builtin_amdgcn_mfma_f32_16x16x32_bf16(af[m], bfr[n], acc2[m][n], 0, 0, 0);
        }
        __syncthreads();
    }

    // ---- epilogue: + b2, scatter-add to agg[row] ----
    #pragma unroll
    for (int m = 0; m < 4; ++m) {
        #pragma unroll
        for (int rr = 0; rr < 4; ++rr) {
            int row = m * 16 + 4 * g + rr;
            int nd = s_src[row];
            float* base = agg + (size_t)nd * NH;
            #pragma unroll
            for (int n = 0; n < 4; ++n) {
                int col = w * 64 + n * 16 + l15;
                atomicAdd(base + col, acc2[m][n][rr] + s_b2[col]);
            }
        }
    }
}

// ---------------- node kernel ----------------
__global__ __launch_bounds__(256, 2)
void node_kernel(const float* __restrict__ h,
                 const unsigned short* __restrict__ hbf,
                 const unsigned short* __restrict__ aggbf,
                 const unsigned short* __restrict__ Wt3,
                 const unsigned short* __restrict__ Wt4,
                 const float* __restrict__ b3, const float* __restrict__ g2,
                 const float* __restrict__ be2, const float* __restrict__ b4,
                 float* __restrict__ out)
{
    __shared__ __align__(16) unsigned short A_lds[64 * 64];
    __shared__ __align__(16) unsigned short B_lds[256 * 64];
    __shared__ __align__(16) unsigned short M_lds[64 * 256];
    __shared__ float s_mr[64][2];
    __shared__ float s_b3[256], s_g2[256], s_be2[256], s_b4[128];

    const int tid = threadIdx.x;
    const int lane = tid & 63;
    const int w = tid >> 6;
    const int l15 = lane & 15;
    const int g = lane >> 4;
    const int r0 = blockIdx.x * 64;

    s_b3[tid] = b3[tid]; s_g2[tid] = g2[tid]; s_be2[tid] = be2[tid];
    if (tid < 128) s_b4[tid] = b4[tid];
    __syncthreads();

    f32x4 acc[4][4] = {};

    // ---- GEMM3: concat(h,agg)[64x384] @ W3 ----
    for (int kt = 0; kt < 6; ++kt) {
        #pragma unroll
        for (int i = 0; i < 2; ++i) {
            int c = i * 256 + w * 64 + lane;
            int r = c >> 3, kbl = c & 7;
            int kb = kbl ^ (r & 7);
            int nd = r0 + r; if (nd >= NNODES) nd = NNODES - 1;
            const unsigned short* src = (kt < 2)
                ? (hbf + nd * NF + kt * 64 + kb * 8)
                : (aggbf + nd * NH + (kt - 2) * 64 + kb * 8);
            gload16(src, &A_lds[(i * 256 + w * 64) * 8]);
        }
        #pragma unroll
        for (int i = 0; i < 8; ++i) {
            int c = i * 256 + w * 64 + lane;
            int n = c >> 3, kbl = c & 7;
            int kb = kbl ^ (n & 7);
            const unsigned short* src = Wt3 + n * 384 + kt * 64 + kb * 8;
            gload16(src, &B_lds[(i * 256 + w * 64) * 8]);
        }
        __syncthreads();
        #pragma unroll
        for (int kk = 0; kk < 2; ++kk) {
            int ke = kk * 32 + 8 * g;
            bf16x8 af[4], bfr[4];
            #pragma unroll
            for (int m = 0; m < 4; ++m) {
                int r = m * 16 + l15;
                af[m] = *(const bf16x8*)(const void*)&A_lds[r * 64 + (ke ^ ((r & 7) << 3))];
            }
            #pragma unroll
            for (int n = 0; n < 4; ++n) {
                int cn = w * 64 + n * 16 + l15;
                bfr[n] = *(const bf16x8*)(const void*)&B_lds[cn * 64 + (ke ^ ((cn & 7) << 3))];
            }
            #pragma unroll
            for (int m = 0; m < 4; ++m)
                #pragma unroll
                for (int n = 0; n < 4; ++n)
                    acc[m][n] = __builtin_amdgcn_mfma_f32_16x16x32_bf16(af[m], bfr[n], acc[m][n], 0, 0, 0);
        }
        __syncthreads();
    }

    // ---- bias + LN stats ----
    float psum[4][4], psq[4][4];
    #pragma unroll
    for (int m = 0; m < 4; ++m)
        #pragma unroll
        for (int rr = 0; rr < 4; ++rr) { psum[m][rr] = 0.f; psq[m][rr] = 0.f; }
    #pragma unroll
    for (int m = 0; m < 4; ++m)
        #pragma unroll
        for (int n = 0; n < 4; ++n) {
            int col = w * 64 + n * 16 + l15;
            float bb = s_b3[col];
            #pragma unroll
            for (int rr = 0; rr < 4; ++rr) {
                float x = acc[m][n][rr] + bb;
                acc[m][n][rr] = x;
                psum[m][rr] += x;
                psq[m][rr] += x * x;
            }
        }
    #pragma unroll
    for (int m = 0; m < 4; ++m)
        #pragma unroll
        for (int rr = 0; rr < 4; ++rr) {
            float s = psum[m][rr], q = psq[m][rr];
            s += __shfl_xor(s, 1); s += __shfl_xor(s, 2); s += __shfl_xor(s, 4); s += __shfl_xor(s, 8);
            q += __shfl_xor(q, 1); q += __shfl_xor(q, 2); q += __shfl_xor(q, 4); q += __shfl_xor(q, 8);
            psum[m][rr] = s; psq[m][rr] = q;
        }
    float vs = 0.f, vq = 0.f;
    #pragma unroll
    for (int m = 0; m < 4; ++m)
        #pragma unroll
        for (int rr = 0; rr < 4; ++rr) {
            bool sel = (l15 == m * 4 + rr);
            vs = sel ? psum[m][rr] : vs;
            vq = sel ? psq[m][rr] : vq;
        }
    float (*s_part)[64][2] = (float(*)[64][2])(void*)M_lds;
    {
        int row = (l15 >> 2) * 16 + 4 * g + (l15 & 3);
        s_part[w][row][0] = vs;
        s_part[w][row][1] = vq;
    }
    __syncthreads();
    if (tid < 64) {
        float s = s_part[0][tid][0] + s_part[1][tid][0] + s_part[2][tid][0] + s_part[3][tid][0];
        float q = s_part[0][tid][1] + s_part[1][tid][1] + s_part[2][tid][1] + s_part[3][tid][1];
        float mean = s * (1.f / 256.f);
        float var = q * (1.f / 256.f) - mean * mean;
        s_mr[tid][0] = mean;
        s_mr[tid][1] = rsqrtf(var + 1e-5f);
    }
    __syncthreads();

    #pragma unroll
    for (int m = 0; m < 4; ++m)
        #pragma unroll
        for (int rr = 0; rr < 4; ++rr) {
            int row = m * 16 + 4 * g + rr;
            float mean = s_mr[row][0], rstd = s_mr[row][1];
            #pragma unroll
            for (int n = 0; n < 4; ++n) {
                int col = w * 64 + n * 16 + l15;
                float y = (acc[m][n][rr] - mean) * rstd * s_g2[col] + s_be2[col];
                float sy = y * (1.f / (1.f + __expf(-y)));
                M_lds[row * 256 + (col ^ ((row & 7) << 3))] = f2bf(sy);
            }
        }
    __syncthreads();

    // ---- GEMM4: m[64x256] @ W4 (N=128, wave w owns cols [w*32, w*32+32)) ----
    f32x4 acc4[4][2] = {};
    for (int kt = 0; kt < 4; ++kt) {
        #pragma unroll
        for (int i = 0; i < 4; ++i) {
            int c = i * 256 + w * 64 + lane;
            int n = c >> 3, kbl = c & 7;
            int kb = kbl ^ (n & 7);
            const unsigned short* src = Wt4 + n * 256 + kt * 64 + kb * 8;
            gload16(src, &B_lds[(i * 256 + w * 64) * 8]);
        }
        __syncthreads();
        #pragma unroll
        for (int kk = 0; kk < 2; ++kk) {
            int keB = kk * 32 + 8 * g;
            int keA = kt * 64 + keB;
            bf16x8 af[4], bfr[2];
            #pragma unroll
            for (int m = 0; m < 4; ++m) {
                int r = m * 16 + l15;
                af[m] = *(const bf16x8*)(const void*)&M_lds[r * 256 + (keA ^ ((r & 7) << 3))];
            }
            #pragma unroll
            for (int n2 = 0; n2 < 2; ++n2) {
                int cn = w * 32 + n2 * 16 + l15;
                bfr[n2] = *(const bf16x8*)(const void*)&B_lds[cn * 64 + (keB ^ ((cn & 7) << 3))];
            }
            #pragma unroll
            for (int m = 0; m < 4; ++m)
                #pragma unroll
                for (int n2 = 0; n2 < 2; ++n2)
                    acc4[m][n2] = __builtin_amdgcn_mfma_f32_16x16x32_bf16(af[m], bfr[n2], acc4[m][n2], 0, 0, 0);
        }
        __syncthreads();
    }

    // ---- epilogue: + b4 + residual ----
    #pragma unroll
    for (int m = 0; m < 4; ++m)
        #pragma unroll
        for (int rr = 0; rr < 4; ++rr) {
            int row = m * 16 + 4 * g + rr;
            int nd = r0 + row;
            if (nd < NNODES) {
                #pragma unroll
                for (int n2 = 0; n2 < 2; ++n2) {
                    int col = w * 32 + n2 * 16 + l15;
                    out[nd * NF + col] = h[nd * NF + col] + acc4[m][n2][rr] + s_b4[col];
                }
            }
        }
}

extern "C" void kernel_launch(void* const* d_in, const int* in_sizes, int n_in,
                              void* d_out, int out_size, void* d_ws, size_t ws_size,
                              hipStream_t stream) {
    const float* h   = (const float*)d_in[0];
    const int* ei    = (const int*)d_in[1];
    const float* W1  = (const float*)d_in[2];
    const float* b1  = (const float*)d_in[3];
    const float* g1  = (const float*)d_in[4];
    const float* be1 = (const float*)d_in[5];
    const float* W2  = (const float*)d_in[6];
    const float* b2  = (const float*)d_in[7];
    const float* W3  = (const float*)d_in[8];
    const float* b3  = (const float*)d_in[9];
    const float* g2  = (const float*)d_in[10];
    const float* be2 = (const float*)d_in[11];
    const float* W4  = (const float*)d_in[12];
    const float* b4  = (const float*)d_in[13];
    float* out = (float*)d_out;

    char* ws = (char*)d_ws;
    float* agg            = (float*)(ws);                    // 51,200,000 B
    unsigned short* hbf   = (unsigned short*)(ws + 51200000); // 12,800,000 B
    unsigned short* aggbf = (unsigned short*)(ws + 64000000); // 25,600,000 B
    unsigned short* Wt1   = (unsigned short*)(ws + 89600000); // 131,072 B
    unsigned short* Wt2   = (unsigned short*)(ws + 89731072); // 131,072 B
    unsigned short* Wt3   = (unsigned short*)(ws + 89862144); // 196,608 B
    unsigned short* Wt4   = (unsigned short*)(ws + 90058752); // 65,536 B

    hipMemsetAsync(agg, 0, (size_t)NNODES * NH * sizeof(float), stream);
    cvt_kernel<<<(NNODES * NF / 4 + 255) / 256, 256, 0, stream>>>(h, hbf, NNODES * NF / 4);
    tcvt_kernel<<<(256 * 256 + 255) / 256, 256, 0, stream>>>(W1, Wt1, 256, 256);
    tcvt_kernel<<<(256 * 256 + 255) / 256, 256, 0, stream>>>(W2, Wt2, 256, 256);
    tcvt_kernel<<<(384 * 256 + 255) / 256, 256, 0, stream>>>(W3, Wt3, 384, 256);
    tcvt_kernel<<<(256 * 128 + 255) / 256, 256, 0, stream>>>(W4, Wt4, 256, 128);
    edge_kernel<<<NEDGES / 64, 256, 0, stream>>>(hbf, ei, Wt1, Wt2, b1, g1, be1, b2, agg);
    cvt_kernel<<<(NNODES * NH / 4 + 255) / 256, 256, 0, stream>>>(agg, aggbf, NNODES * NH / 4);
    node_kernel<<<(NNODES + 63) / 64, 256, 0, stream>>>(h, hbf, aggbf, Wt3, Wt4, b3, g2, be2, b4, out);
}

// Round 2
// 769.808 us; speedup vs baseline: 1.1268x; 1.1268x over previous
//
#include <hip/hip_runtime.h>
#include <hip/hip_bf16.h>
#include <stdint.h>

#define NNODES 50000
#define NEDGES 800000
#define NF 128
#define NH 256

typedef __attribute__((ext_vector_type(8))) __bf16 bf16x8;
typedef __attribute__((ext_vector_type(4))) float f32x4;

__device__ __forceinline__ unsigned short f2bf(float f) {
    union { float f; unsigned int u; } v; v.f = f;
    unsigned int r = v.u + 0x7fffu + ((v.u >> 16) & 1u);
    return (unsigned short)(r >> 16);
}

__device__ __forceinline__ void gload16(const void* g, void* l) {
    __builtin_amdgcn_global_load_lds(
        (const __attribute__((address_space(1))) void*)g,
        (__attribute__((address_space(3))) void*)l,
        16, 0, 0);
}

// f32 -> bf16 (vectorized), n4 = count of float4 groups
__global__ __launch_bounds__(256) void cvt_kernel(const float* __restrict__ src,
                                                  unsigned short* __restrict__ dst, int n4) {
    int i = blockIdx.x * 256 + threadIdx.x;
    if (i < n4) {
        const float4 v = ((const float4*)src)[i];
        ushort4 o;
        o.x = f2bf(v.x); o.y = f2bf(v.y); o.z = f2bf(v.z); o.w = f2bf(v.w);
        ((ushort4*)dst)[i] = o;
    }
}

// W [K][Nn] f32 row-major -> Wt [Nn][K] bf16
__global__ __launch_bounds__(256) void tcvt_kernel(const float* __restrict__ W,
                                                   unsigned short* __restrict__ Wt, int K, int Nn) {
    int i = blockIdx.x * 256 + threadIdx.x;
    if (i < K * Nn) {
        int k = i / Nn, n = i - k * Nn;
        Wt[n * K + k] = f2bf(W[i]);
    }
}

// ---------------- sort-by-row kernels ----------------
__global__ __launch_bounds__(256) void hist_kernel(const int* __restrict__ row, int* __restrict__ cnt) {
    int e = blockIdx.x * 256 + threadIdx.x;
    if (e < NEDGES) atomicAdd(&cnt[row[e]], 1);
}

// single-block exclusive prefix sum over n counts (n ~ 50000), 1024 threads
__global__ __launch_bounds__(1024) void scan_kernel(const int* __restrict__ cnt, int* __restrict__ base, int n) {
    __shared__ int wsum[16];
    __shared__ int s_carry;
    const int tid = threadIdx.x;
    const int lane = tid & 63;
    const int wv = tid >> 6;
    if (tid == 0) s_carry = 0;
    __syncthreads();
    for (int off = 0; off < n; off += 1024) {
        int v = (off + tid < n) ? cnt[off + tid] : 0;
        int acc = v;
        #pragma unroll
        for (int s = 1; s < 64; s <<= 1) {
            int t = __shfl_up(acc, s);
            if (lane >= s) acc += t;
        }
        if (lane == 63) wsum[wv] = acc;
        __syncthreads();
        if (wv == 0) {
            int x = (lane < 16) ? wsum[lane] : 0;
            #pragma unroll
            for (int s = 1; s < 16; s <<= 1) {
                int t = __shfl_up(x, s);
                if (lane >= s) x += t;
            }
            if (lane < 16) wsum[lane] = x;
        }
        __syncthreads();
        int c = s_carry;
        int wtot = __shfl(acc, 63);
        int woff = wsum[wv] - wtot;
        if (off + tid < n) base[off + tid] = c + woff + acc - v;
        __syncthreads();
        if (tid == 0) s_carry = c + wsum[15];
        __syncthreads();
    }
}

__global__ __launch_bounds__(256) void scatter_kernel(const int* __restrict__ ei,
                                                      const int* __restrict__ base,
                                                      int* __restrict__ cursor,
                                                      int* __restrict__ ssrc,
                                                      int* __restrict__ sdst) {
    int e = blockIdx.x * 256 + threadIdx.x;
    if (e < NEDGES) {
        int r = ei[e];
        int c = ei[NEDGES + e];
        int pos = base[r] + atomicAdd(&cursor[r], 1);
        ssrc[pos] = r;
        sdst[pos] = c;
    }
}

// ---------------- edge kernel ----------------
// 64 sorted edges per block, 4 waves, wave w owns output cols [w*64, w*64+64)
__global__ __launch_bounds__(256, 2)
void edge_kernel(const unsigned short* __restrict__ hbf,
                 const int* __restrict__ ssrc,
                 const int* __restrict__ sdst,
                 const unsigned short* __restrict__ Wt1,
                 const unsigned short* __restrict__ Wt2,
                 const float* __restrict__ b1, const float* __restrict__ g1,
                 const float* __restrict__ be1, const float* __restrict__ b2,
                 float* __restrict__ agg)
{
    // GEMM region: A (8192 B) | B (32768 B) | M (32768 B) = 73728 B
    // epilogue overlays a 64x260 f32 tile (66560 B) on the same region
    __shared__ __align__(16) char smem[73728];
    unsigned short* A_lds = (unsigned short*)smem;
    unsigned short* B_lds = (unsigned short*)(smem + 8192);
    unsigned short* M_lds = (unsigned short*)(smem + 40960);
    float* S = (float*)smem;
    __shared__ int s_src[64], s_dst[64];
    __shared__ float s_mr[64][2];
    __shared__ float s_b1[256], s_g1[256], s_be1[256], s_b2[256];

    const int tid = threadIdx.x;
    const int lane = tid & 63;
    const int w = tid >> 6;
    const int l15 = lane & 15;
    const int g = lane >> 4;
    const int e0 = blockIdx.x * 64;

    if (tid < 64) s_src[tid] = ssrc[e0 + tid];
    else if (tid < 128) s_dst[tid - 64] = sdst[e0 + (tid - 64)];
    s_b1[tid] = b1[tid]; s_g1[tid] = g1[tid]; s_be1[tid] = be1[tid]; s_b2[tid] = b2[tid];
    __syncthreads();

    f32x4 acc[4][4] = {};

    // ---- GEMM1: e_in[64x256] @ W1 ----
    for (int kt = 0; kt < 4; ++kt) {
        #pragma unroll
        for (int i = 0; i < 2; ++i) {
            int c = i * 256 + w * 64 + lane;
            int r = c >> 3, kbl = c & 7;
            int kb = kbl ^ (r & 7);
            int nd = (kt < 2) ? s_src[r] : s_dst[r];
            const unsigned short* src = hbf + nd * NF + (kt & 1) * 64 + kb * 8;
            gload16(src, &A_lds[(i * 256 + w * 64) * 8]);
        }
        #pragma unroll
        for (int i = 0; i < 8; ++i) {
            int c = i * 256 + w * 64 + lane;
            int n = c >> 3, kbl = c & 7;
            int kb = kbl ^ (n & 7);
            const unsigned short* src = Wt1 + n * 256 + kt * 64 + kb * 8;
            gload16(src, &B_lds[(i * 256 + w * 64) * 8]);
        }
        __syncthreads();
        #pragma unroll
        for (int kk = 0; kk < 2; ++kk) {
            int ke = kk * 32 + 8 * g;
            bf16x8 af[4], bfr[4];
            #pragma unroll
            for (int m = 0; m < 4; ++m) {
                int r = m * 16 + l15;
                af[m] = *(const bf16x8*)(const void*)&A_lds[r * 64 + (ke ^ ((r & 7) << 3))];
            }
            #pragma unroll
            for (int n = 0; n < 4; ++n) {
                int cn = w * 64 + n * 16 + l15;
                bfr[n] = *(const bf16x8*)(const void*)&B_lds[cn * 64 + (ke ^ ((cn & 7) << 3))];
            }
            #pragma unroll
            for (int m = 0; m < 4; ++m)
                #pragma unroll
                for (int n = 0; n < 4; ++n)
                    acc[m][n] = __builtin_amdgcn_mfma_f32_16x16x32_bf16(af[m], bfr[n], acc[m][n], 0, 0, 0);
        }
        __syncthreads();
    }

    // ---- bias + LayerNorm stats ----
    float psum[4][4], psq[4][4];
    #pragma unroll
    for (int m = 0; m < 4; ++m)
        #pragma unroll
        for (int rr = 0; rr < 4; ++rr) { psum[m][rr] = 0.f; psq[m][rr] = 0.f; }
    #pragma unroll
    for (int m = 0; m < 4; ++m)
        #pragma unroll
        for (int n = 0; n < 4; ++n) {
            int col = w * 64 + n * 16 + l15;
            float bb = s_b1[col];
            #pragma unroll
            for (int rr = 0; rr < 4; ++rr) {
                float x = acc[m][n][rr] + bb;
                acc[m][n][rr] = x;
                psum[m][rr] += x;
                psq[m][rr] += x * x;
            }
        }
    #pragma unroll
    for (int m = 0; m < 4; ++m)
        #pragma unroll
        for (int rr = 0; rr < 4; ++rr) {
            float s = psum[m][rr], q = psq[m][rr];
            s += __shfl_xor(s, 1); s += __shfl_xor(s, 2); s += __shfl_xor(s, 4); s += __shfl_xor(s, 8);
            q += __shfl_xor(q, 1); q += __shfl_xor(q, 2); q += __shfl_xor(q, 4); q += __shfl_xor(q, 8);
            psum[m][rr] = s; psq[m][rr] = q;
        }
    float vs = 0.f, vq = 0.f;
    #pragma unroll
    for (int m = 0; m < 4; ++m)
        #pragma unroll
        for (int rr = 0; rr < 4; ++rr) {
            bool sel = (l15 == m * 4 + rr);
            vs = sel ? psum[m][rr] : vs;
            vq = sel ? psq[m][rr] : vq;
        }
    float (*s_part)[64][2] = (float(*)[64][2])(void*)M_lds;  // overlay, dead before M writes
    {
        int row = (l15 >> 2) * 16 + 4 * g + (l15 & 3);
        s_part[w][row][0] = vs;
        s_part[w][row][1] = vq;
    }
    __syncthreads();
    if (tid < 64) {
        float s = s_part[0][tid][0] + s_part[1][tid][0] + s_part[2][tid][0] + s_part[3][tid][0];
        float q = s_part[0][tid][1] + s_part[1][tid][1] + s_part[2][tid][1] + s_part[3][tid][1];
        float mean = s * (1.f / 256.f);
        float var = q * (1.f / 256.f) - mean * mean;
        s_mr[tid][0] = mean;
        s_mr[tid][1] = rsqrtf(var + 1e-5f);
    }
    __syncthreads();

    // ---- LN apply + SiLU + write m tile (bf16, swizzled) ----
    #pragma unroll
    for (int m = 0; m < 4; ++m)
        #pragma unroll
        for (int rr = 0; rr < 4; ++rr) {
            int row = m * 16 + 4 * g + rr;
            float mean = s_mr[row][0], rstd = s_mr[row][1];
            #pragma unroll
            for (int n = 0; n < 4; ++n) {
                int col = w * 64 + n * 16 + l15;
                float y = (acc[m][n][rr] - mean) * rstd * s_g1[col] + s_be1[col];
                float sy = y * (1.f / (1.f + __expf(-y)));
                M_lds[row * 256 + (col ^ ((row & 7) << 3))] = f2bf(sy);
            }
        }
    __syncthreads();

    // ---- GEMM2: m[64x256] @ W2 ----
    f32x4 acc2[4][4] = {};
    for (int kt = 0; kt < 4; ++kt) {
        #pragma unroll
        for (int i = 0; i < 8; ++i) {
            int c = i * 256 + w * 64 + lane;
            int n = c >> 3, kbl = c & 7;
            int kb = kbl ^ (n & 7);
            const unsigned short* src = Wt2 + n * 256 + kt * 64 + kb * 8;
            gload16(src, &B_lds[(i * 256 + w * 64) * 8]);
        }
        __syncthreads();
        #pragma unroll
        for (int kk = 0; kk < 2; ++kk) {
            int keB = kk * 32 + 8 * g;
            int keA = kt * 64 + keB;
            bf16x8 af[4], bfr[4];
            #pragma unroll
            for (int m = 0; m < 4; ++m) {
                int r = m * 16 + l15;
                af[m] = *(const bf16x8*)(const void*)&M_lds[r * 256 + (keA ^ ((r & 7) << 3))];
            }
            #pragma unroll
            for (int n = 0; n < 4; ++n) {
                int cn = w * 64 + n * 16 + l15;
                bfr[n] = *(const bf16x8*)(const void*)&B_lds[cn * 64 + (keB ^ ((cn & 7) << 3))];
            }
            #pragma unroll
            for (int m = 0; m < 4; ++m)
                #pragma unroll
                for (int n = 0; n < 4; ++n)
                    acc2[m][n] = __builtin_amdgcn_mfma_f32_16x16x32_bf16(af[m], bfr[n], acc2[m][n], 0, 0, 0);
        }
        __syncthreads();
    }

    // ---- epilogue: write (acc2+b2) to LDS f32 tile, run-reduce sorted rows, one atomic per run ----
    #pragma unroll
    for (int m = 0; m < 4; ++m) {
        #pragma unroll
        for (int rr = 0; rr < 4; ++rr) {
            int row = m * 16 + 4 * g + rr;
            #pragma unroll
            for (int n = 0; n < 4; ++n) {
                int col = w * 64 + n * 16 + l15;
                S[row * 260 + col] = acc2[m][n][rr] + s_b2[col];
            }
        }
    }
    __syncthreads();
    {
        int col = tid;   // 256 threads, one column each
        float run = 0.f;
        int prev = s_src[0];
        #pragma unroll 1
        for (int r = 0; r < 64; ++r) {
            int nd = s_src[r];
            if (nd != prev) {
                atomicAdd(&agg[(size_t)prev * NH + col], run);
                run = 0.f;
                prev = nd;
            }
            run += S[r * 260 + col];
        }
        atomicAdd(&agg[(size_t)prev * NH + col], run);
    }
}

// ---------------- node kernel ----------------
__global__ __launch_bounds__(256, 2)
void node_kernel(const float* __restrict__ h,
                 const unsigned short* __restrict__ hbf,
                 const unsigned short* __restrict__ aggbf,
                 const unsigned short* __restrict__ Wt3,
                 const unsigned short* __restrict__ Wt4,
                 const float* __restrict__ b3, const float* __restrict__ g2,
                 const float* __restrict__ be2, const float* __restrict__ b4,
                 float* __restrict__ out)
{
    __shared__ __align__(16) unsigned short A_lds[64 * 64];
    __shared__ __align__(16) unsigned short B_lds[256 * 64];
    __shared__ __align__(16) unsigned short M_lds[64 * 256];
    __shared__ float s_mr[64][2];
    __shared__ float s_b3[256], s_g2[256], s_be2[256], s_b4[128];

    const int tid = threadIdx.x;
    const int lane = tid & 63;
    const int w = tid >> 6;
    const int l15 = lane & 15;
    const int g = lane >> 4;
    const int r0 = blockIdx.x * 64;

    s_b3[tid] = b3[tid]; s_g2[tid] = g2[tid]; s_be2[tid] = be2[tid];
    if (tid < 128) s_b4[tid] = b4[tid];
    __syncthreads();

    f32x4 acc[4][4] = {};

    // ---- GEMM3: concat(h,agg)[64x384] @ W3 ----
    for (int kt = 0; kt < 6; ++kt) {
        #pragma unroll
        for (int i = 0; i < 2; ++i) {
            int c = i * 256 + w * 64 + lane;
            int r = c >> 3, kbl = c & 7;
            int kb = kbl ^ (r & 7);
            int nd = r0 + r; if (nd >= NNODES) nd = NNODES - 1;
            const unsigned short* src = (kt < 2)
                ? (hbf + nd * NF + kt * 64 + kb * 8)
                : (aggbf + nd * NH + (kt - 2) * 64 + kb * 8);
            gload16(src, &A_lds[(i * 256 + w * 64) * 8]);
        }
        #pragma unroll
        for (int i = 0; i < 8; ++i) {
            int c = i * 256 + w * 64 + lane;
            int n = c >> 3, kbl = c & 7;
            int kb = kbl ^ (n & 7);
            const unsigned short* src = Wt3 + n * 384 + kt * 64 + kb * 8;
            gload16(src, &B_lds[(i * 256 + w * 64) * 8]);
        }
        __syncthreads();
        #pragma unroll
        for (int kk = 0; kk < 2; ++kk) {
            int ke = kk * 32 + 8 * g;
            bf16x8 af[4], bfr[4];
            #pragma unroll
            for (int m = 0; m < 4; ++m) {
                int r = m * 16 + l15;
                af[m] = *(const bf16x8*)(const void*)&A_lds[r * 64 + (ke ^ ((r & 7) << 3))];
            }
            #pragma unroll
            for (int n = 0; n < 4; ++n) {
                int cn = w * 64 + n * 16 + l15;
                bfr[n] = *(const bf16x8*)(const void*)&B_lds[cn * 64 + (ke ^ ((cn & 7) << 3))];
            }
            #pragma unroll
            for (int m = 0; m < 4; ++m)
                #pragma unroll
                for (int n = 0; n < 4; ++n)
                    acc[m][n] = __builtin_amdgcn_mfma_f32_16x16x32_bf16(af[m], bfr[n], acc[m][n], 0, 0, 0);
        }
        __syncthreads();
    }

    // ---- bias + LN stats ----
    float psum[4][4], psq[4][4];
    #pragma unroll
    for (int m = 0; m < 4; ++m)
        #pragma unroll
        for (int rr = 0; rr < 4; ++rr) { psum[m][rr] = 0.f; psq[m][rr] = 0.f; }
    #pragma unroll
    for (int m = 0; m < 4; ++m)
        #pragma unroll
        for (int n = 0; n < 4; ++n) {
            int col = w * 64 + n * 16 + l15;
            float bb = s_b3[col];
            #pragma unroll
            for (int rr = 0; rr < 4; ++rr) {
                float x = acc[m][n][rr] + bb;
                acc[m][n][rr] = x;
                psum[m][rr] += x;
                psq[m][rr] += x * x;
            }
        }
    #pragma unroll
    for (int m = 0; m < 4; ++m)
        #pragma unroll
        for (int rr = 0; rr < 4; ++rr) {
            float s = psum[m][rr], q = psq[m][rr];
            s += __shfl_xor(s, 1); s += __shfl_xor(s, 2); s += __shfl_xor(s, 4); s += __shfl_xor(s, 8);
            q += __shfl_xor(q, 1); q += __shfl_xor(q, 2); q += __shfl_xor(q, 4); q += __shfl_xor(q, 8);
            psum[m][rr] = s; psq[m][rr] = q;
        }
    float vs = 0.f, vq = 0.f;
    #pragma unroll
    for (int m = 0; m < 4; ++m)
        #pragma unroll
        for (int rr = 0; rr < 4; ++rr) {
            bool sel = (l15 == m * 4 + rr);
            vs = sel ? psum[m][rr] : vs;
            vq = sel ? psq[m][rr] : vq;
        }
    float (*s_part)[64][2] = (float(*)[64][2])(void*)M_lds;
    {
        int row = (l15 >> 2) * 16 + 4 * g + (l15 & 3);
        s_part[w][row][0] = vs;
        s_part[w][row][1] = vq;
    }
    __syncthreads();
    if (tid < 64) {
        float s = s_part[0][tid][0] + s_part[1][tid][0] + s_part[2][tid][0] + s_part[3][tid][0];
        float q = s_part[0][tid][1] + s_part[1][tid][1] + s_part[2][tid][1] + s_part[3][tid][1];
        float mean = s * (1.f / 256.f);
        float var = q * (1.f / 256.f) - mean * mean;
        s_mr[tid][0] = mean;
        s_mr[tid][1] = rsqrtf(var + 1e-5f);
    }
    __syncthreads();

    #pragma unroll
    for (int m = 0; m < 4; ++m)
        #pragma unroll
        for (int rr = 0; rr < 4; ++rr) {
            int row = m * 16 + 4 * g + rr;
            float mean = s_mr[row][0], rstd = s_mr[row][1];
            #pragma unroll
            for (int n = 0; n < 4; ++n) {
                int col = w * 64 + n * 16 + l15;
                float y = (acc[m][n][rr] - mean) * rstd * s_g2[col] + s_be2[col];
                float sy = y * (1.f / (1.f + __expf(-y)));
                M_lds[row * 256 + (col ^ ((row & 7) << 3))] = f2bf(sy);
            }
        }
    __syncthreads();

    // ---- GEMM4: m[64x256] @ W4 (N=128, wave w owns cols [w*32, w*32+32)) ----
    f32x4 acc4[4][2] = {};
    for (int kt = 0; kt < 4; ++kt) {
        #pragma unroll
        for (int i = 0; i < 4; ++i) {
            int c = i * 256 + w * 64 + lane;
            int n = c >> 3, kbl = c & 7;
            int kb = kbl ^ (n & 7);
            const unsigned short* src = Wt4 + n * 256 + kt * 64 + kb * 8;
            gload16(src, &B_lds[(i * 256 + w * 64) * 8]);
        }
        __syncthreads();
        #pragma unroll
        for (int kk = 0; kk < 2; ++kk) {
            int keB = kk * 32 + 8 * g;
            int keA = kt * 64 + keB;
            bf16x8 af[4], bfr[2];
            #pragma unroll
            for (int m = 0; m < 4; ++m) {
                int r = m * 16 + l15;
                af[m] = *(const bf16x8*)(const void*)&M_lds[r * 256 + (keA ^ ((r & 7) << 3))];
            }
            #pragma unroll
            for (int n2 = 0; n2 < 2; ++n2) {
                int cn = w * 32 + n2 * 16 + l15;
                bfr[n2] = *(const bf16x8*)(const void*)&B_lds[cn * 64 + (keB ^ ((cn & 7) << 3))];
            }
            #pragma unroll
            for (int m = 0; m < 4; ++m)
                #pragma unroll
                for (int n2 = 0; n2 < 2; ++n2)
                    acc4[m][n2] = __builtin_amdgcn_mfma_f32_16x16x32_bf16(af[m], bfr[n2], acc4[m][n2], 0, 0, 0);
        }
        __syncthreads();
    }

    // ---- epilogue: + b4 + residual ----
    #pragma unroll
    for (int m = 0; m < 4; ++m)
        #pragma unroll
        for (int rr = 0; rr < 4; ++rr) {
            int row = m * 16 + 4 * g + rr;
            int nd = r0 + row;
            if (nd < NNODES) {
                #pragma unroll
                for (int n2 = 0; n2 < 2; ++n2) {
                    int col = w * 32 + n2 * 16 + l15;
                    out[nd * NF + col] = h[nd * NF + col] + acc4[m][n2][rr] + s_b4[col];
                }
            }
        }
}

extern "C" void kernel_launch(void* const* d_in, const int* in_sizes, int n_in,
                              void* d_out, int out_size, void* d_ws, size_t ws_size,
                              hipStream_t stream) {
    const float* h   = (const float*)d_in[0];
    const int* ei    = (const int*)d_in[1];
    const float* W1  = (const float*)d_in[2];
    const float* b1  = (const float*)d_in[3];
    const float* g1  = (const float*)d_in[4];
    const float* be1 = (const float*)d_in[5];
    const float* W2  = (const float*)d_in[6];
    const float* b2  = (const float*)d_in[7];
    const float* W3  = (const float*)d_in[8];
    const float* b3  = (const float*)d_in[9];
    const float* g2  = (const float*)d_in[10];
    const float* be2 = (const float*)d_in[11];
    const float* W4  = (const float*)d_in[12];
    const float* b4  = (const float*)d_in[13];
    float* out = (float*)d_out;

    char* ws = (char*)d_ws;
    float* agg            = (float*)(ws);                      // 51,200,000 B
    unsigned short* hbf   = (unsigned short*)(ws + 51200000);  // 12,800,000 B
    unsigned short* aggbf = (unsigned short*)(ws + 64000000);  // 25,600,000 B
    // ssrc/sdst overlay aggbf: live only [scatter, edge_kernel]; aggbf live [cvt2, node_kernel]
    int* ssrc             = (int*)(ws + 64000000);             // 3,200,000 B
    int* sdst             = (int*)(ws + 67200000);             // 3,200,000 B
    unsigned short* Wt1   = (unsigned short*)(ws + 89600000);  // 131,072 B
    unsigned short* Wt2   = (unsigned short*)(ws + 89731072);  // 131,072 B
    unsigned short* Wt3   = (unsigned short*)(ws + 89862144);  // 196,608 B
    unsigned short* Wt4   = (unsigned short*)(ws + 90058752);  // 65,536 B
    int* cnt              = (int*)(ws + 90124288);             // 200,000 B
    int* basep            = (int*)(ws + 90324288);             // 200,000 B
    int* cursor           = (int*)(ws + 90524288);             // 200,000 B  (end ~90.72 MB)

    hipMemsetAsync(agg, 0, (size_t)NNODES * NH * sizeof(float), stream);
    hipMemsetAsync(cnt, 0, NNODES * sizeof(int), stream);
    hipMemsetAsync(cursor, 0, NNODES * sizeof(int), stream);

    cvt_kernel<<<(NNODES * NF / 4 + 255) / 256, 256, 0, stream>>>(h, hbf, NNODES * NF / 4);
    tcvt_kernel<<<(256 * 256 + 255) / 256, 256, 0, stream>>>(W1, Wt1, 256, 256);
    tcvt_kernel<<<(256 * 256 + 255) / 256, 256, 0, stream>>>(W2, Wt2, 256, 256);
    tcvt_kernel<<<(384 * 256 + 255) / 256, 256, 0, stream>>>(W3, Wt3, 384, 256);
    tcvt_kernel<<<(256 * 128 + 255) / 256, 256, 0, stream>>>(W4, Wt4, 256, 128);

    hist_kernel<<<(NEDGES + 255) / 256, 256, 0, stream>>>(ei, cnt);
    scan_kernel<<<1, 1024, 0, stream>>>(cnt, basep, NNODES);
    scatter_kernel<<<(NEDGES + 255) / 256, 256, 0, stream>>>(ei, basep, cursor, ssrc, sdst);

    edge_kernel<<<NEDGES / 64, 256, 0, stream>>>(hbf, ssrc, sdst, Wt1, Wt2, b1, g1, be1, b2, agg);
    cvt_kernel<<<(NNODES * NH / 4 + 255) / 256, 256, 0, stream>>>(agg, aggbf, NNODES * NH / 4);
    node_kernel<<<(NNODES + 63) / 64, 256, 0, stream>>>(h, hbf, aggbf, Wt3, Wt4, b3, g2, be2, b4, out);
}